// Round 1
// baseline (3086.898 us; speedup 1.0000x reference)
//
#include <hip/hip_runtime.h>
#include <cstddef>

#define Bn 32
#define Sn 2048
#define Hn 256
#define Ln 2

__device__ __forceinline__ float tanh_fast(float x) {
  // tanh(x) = 1 - 2/(exp(2x)+1); saturates correctly at +/-inf
  float e = __expf(2.0f * x);
  return 1.0f - 2.0f / (e + 1.0f);
}

// ---------------------------------------------------------------------------
// Projection GEMM: C[M,N] = A[M,K] * W[N,K]^T + bias[N]   (unchanged)
// ---------------------------------------------------------------------------
__global__ __launch_bounds__(256) void proj_gemm(
    const float* __restrict__ A,
    const float* __restrict__ W,
    const float* __restrict__ bias,
    float* __restrict__ C)
{
  __shared__ float As[64][68];
  __shared__ float Bs[64][68];
  const int tid = threadIdx.x;
  const int tx = tid & 15;   // N direction
  const int ty = tid >> 4;   // M direction
  const size_t m0 = (size_t)blockIdx.y * 64;
  const int n0 = blockIdx.x * 64;

  float acc[4][4];
#pragma unroll
  for (int i = 0; i < 4; ++i)
#pragma unroll
    for (int j = 0; j < 4; ++j) acc[i][j] = 0.0f;

  for (int kc = 0; kc < Hn; kc += 64) {
#pragma unroll
    for (int r = 0; r < 4; ++r) {
      int idx = tid + 256 * r;
      int mm = idx >> 4;
      int kk = (idx & 15) << 2;
      float4 av = *(const float4*)&A[(m0 + (size_t)mm) * Hn + kc + kk];
      As[kk + 0][mm] = av.x; As[kk + 1][mm] = av.y;
      As[kk + 2][mm] = av.z; As[kk + 3][mm] = av.w;
      float4 wv = *(const float4*)&W[(size_t)(n0 + mm) * Hn + kc + kk];
      Bs[kk + 0][mm] = wv.x; Bs[kk + 1][mm] = wv.y;
      Bs[kk + 2][mm] = wv.z; Bs[kk + 3][mm] = wv.w;
    }
    __syncthreads();
#pragma unroll
    for (int k = 0; k < 64; ++k) {
      float4 a = *(const float4*)&As[k][ty << 2];
      float4 b = *(const float4*)&Bs[k][tx << 2];
      float av4[4] = {a.x, a.y, a.z, a.w};
      float bv4[4] = {b.x, b.y, b.z, b.w};
#pragma unroll
      for (int i = 0; i < 4; ++i)
#pragma unroll
        for (int j = 0; j < 4; ++j)
          acc[i][j] += av4[i] * bv4[j];
    }
    __syncthreads();
  }

  float4 bv = *(const float4*)&bias[n0 + (tx << 2)];
  float badd[4] = {bv.x, bv.y, bv.z, bv.w};
#pragma unroll
  for (int i = 0; i < 4; ++i) {
    float4 o;
    o.x = acc[i][0] + badd[0];
    o.y = acc[i][1] + badd[1];
    o.z = acc[i][2] + badd[2];
    o.w = acc[i][3] + badd[3];
    *(float4*)&C[(m0 + (size_t)((ty << 2) + i)) * Hn + n0 + (tx << 2)] = o;
  }
}

// ---------------------------------------------------------------------------
// Recurrence: one workgroup per batch, 1024 threads (16 waves).
// SINGLE barrier per step:
//   - wave w consumes h[16w..16w+16) (its k-chunk) AND owns outputs
//     [16w..16w+16) in the reduce -> the h-update for its own next-step hv
//     is wave-local (same-wave LDS ops are in order; no 2nd barrier).
//   - partials double-buffered (s&1) so one barrier/step is WAR-safe:
//     a wave's pre-barrier lgkmcnt(0) drains its reads of the buffer before
//     any wave can pass that barrier and overwrite it two steps later.
//   - partial rows: 16 slots at word-stride 20 (80 B, 16B-aligned ->
//     ds_read_b128; 20 mod 32 spreads rows over banks, <=2-way aliasing).
//     slot = w ^ (o&15) ^ ((o>>4)&3): XOR swizzle de-conflicts the scalar
//     writes; sum over slots is permutation-invariant so readers just add
//     the whole row.
//   - raw s_barrier + asm lgkmcnt(0): NO vmcnt drain -> y stores and the
//     prefetched xp load stay in flight across the barrier.
//   - reduce/tanh/y-store spread over all 16 waves (lane<16 of each wave).
// ---------------------------------------------------------------------------
#define PSTRIDE 20            // words per partial-row (16 slots + 4 pad)
#define PWAVE   (16 * PSTRIDE)  // words per wave region (16 rows)
#define PBUF    (16 * PWAVE)    // words per buffer (16 regions)

__global__ __launch_bounds__(1024) void rnn_rec(
    const float* __restrict__ xp,   // [Bn,Sn,Hn] precomputed input projection
    const float* __restrict__ Whh,  // [Hn,Hn]
    const float* __restrict__ bhh,  // [Hn]
    const float* __restrict__ h0,   // [Bn,Hn] (layer slice)
    float* __restrict__ y,          // [Bn,Sn,Hn] layer outputs
    float* __restrict__ hfin)       // [Bn,Hn] final hidden (layer slice)
{
  const int b = blockIdx.x;
  const int t = threadIdx.x;
  const int lane = t & 63;
  const int w = t >> 6;

  __shared__ float part[2 * PBUF];  // 2 x 20 KiB
  __shared__ float hbuf[Hn];

  // Wreg[r][c] = Whh[lane + 64r][16w + c]  (64 regs/thread = whole W on CU)
  float Wreg[4][16];
#pragma unroll
  for (int r = 0; r < 4; ++r)
#pragma unroll
    for (int q = 0; q < 4; ++q) {
      float4 v = *(const float4*)&Whh[(size_t)(lane + 64 * r) * Hn + 16 * w + 4 * q];
      Wreg[r][4 * q + 0] = v.x; Wreg[r][4 * q + 1] = v.y;
      Wreg[r][4 * q + 2] = v.z; Wreg[r][4 * q + 3] = v.w;
    }

  // partial-write word offsets (buffer 0); +PBUF when s odd
  int pw[4];
#pragma unroll
  for (int r = 0; r < 4; ++r) {
    int o = lane + 64 * r;
    int reg = o >> 4;
    int row = o & 15;
    int slot = (w ^ row ^ (reg & 3)) & 15;
    pw[r] = reg * PWAVE + row * PSTRIDE + slot;
  }

  const float* xp_b = xp + (size_t)b * Sn * Hn;
  float* y_b = y + (size_t)b * Sn * Hn;

  const int lr = lane & 15;         // reduce-lane id
  const int ocol = 16 * w + lr;     // output owned by this lane (if lane<16)
  const float bias = bhh[ocol];

  // initial hv from h0 (wave-uniform broadcast loads)
  float hv[16];
#pragma unroll
  for (int j = 0; j < 4; ++j)
    *(float4*)&hv[4 * j] = *(const float4*)&h0[(size_t)b * Hn + 16 * w + 4 * j];

  float xp_cur = xp_b[ocol];

  for (int s = 0; s < Sn; ++s) {
    // prefetch next step's xp; consumed after the barrier -> latency hidden
    float xp_next = (s + 1 < Sn) ? xp_b[(size_t)(s + 1) * Hn + ocol] : 0.0f;

    // ---- FMA phase: 64 fp32 FMAs/lane, all operands in registers
    float a0 = 0.f, a1 = 0.f, a2 = 0.f, a3 = 0.f;
#pragma unroll
    for (int c = 0; c < 16; ++c) {
      a0 += Wreg[0][c] * hv[c];
      a1 += Wreg[1][c] * hv[c];
      a2 += Wreg[2][c] * hv[c];
      a3 += Wreg[3][c] * hv[c];
    }
    float* pbuf = &part[(s & 1) * PBUF];
    pbuf[pw[0]] = a0; pbuf[pw[1]] = a1; pbuf[pw[2]] = a2; pbuf[pw[3]] = a3;

    // partials visible to all waves; no vmcnt drain (y/xp stay in flight)
    asm volatile("s_waitcnt lgkmcnt(0)" ::: "memory");
    __builtin_amdgcn_s_barrier();
    __builtin_amdgcn_sched_barrier(0);

    // ---- reduce + tanh + state update: lane<16 of EVERY wave, own outputs
    if (lane < 16) {
      const float* prow = &pbuf[w * PWAVE + lr * PSTRIDE];
      float4 p0 = *(const float4*)&prow[0];
      float4 p1 = *(const float4*)&prow[4];
      float4 p2 = *(const float4*)&prow[8];
      float4 p3 = *(const float4*)&prow[12];
      float s0 = (p0.x + p0.y) + (p0.z + p0.w);
      float s1 = (p1.x + p1.y) + (p1.z + p1.w);
      float s2 = (p2.x + p2.y) + (p2.z + p2.w);
      float s3 = (p3.x + p3.y) + (p3.z + p3.w);
      float hn = tanh_fast(((s0 + s1) + (s2 + s3)) + xp_cur + bias);
      hbuf[ocol] = hn;
      y_b[(size_t)s * Hn + ocol] = hn;   // fire-and-forget global store
    }
    xp_cur = xp_next;

    // ---- wave-local hv reload (reads only this wave's own 16 outputs)
    __builtin_amdgcn_wave_barrier();   // keep reads after the masked write
#pragma unroll
    for (int j = 0; j < 4; ++j)
      *(float4*)&hv[4 * j] = *(const float4*)&hbuf[16 * w + 4 * j];
  }

  if (lane < 16) hfin[(size_t)b * Hn + ocol] = hbuf[ocol];
}

// ---------------------------------------------------------------------------
// Phases (stream-ordered):
//  1. proj1: xp1 = x * Wih0^T + bih0          -> ws
//  2. rec1 : layer-1 recurrence, y1 -> d_out, fin0 -> d_out tail
//  3. proj2: xp2 = y1 * Wih1^T + bih1         -> ws (reuse)
//  4. rec2 : layer-2 recurrence, y2 -> d_out (final), fin1 -> d_out tail
// ws needs Bn*Sn*Hn*4 = 64 MiB.
// ---------------------------------------------------------------------------
extern "C" void kernel_launch(void* const* d_in, const int* in_sizes, int n_in,
                              void* d_out, int out_size, void* d_ws, size_t ws_size,
                              hipStream_t stream) {
  const float* x   = (const float*)d_in[0];
  const float* h0  = (const float*)d_in[1];
  const float* Wih = (const float*)d_in[2];
  const float* Whh = (const float*)d_in[3];
  const float* bih = (const float*)d_in[4];
  const float* bhh = (const float*)d_in[5];

  float* out = (float*)d_out;
  float* yout = out;                              // [Bn,Sn,Hn]
  float* fin  = out + (size_t)Bn * Sn * Hn;       // [Ln,Bn,Hn]
  float* xpws = (float*)d_ws;                     // [Bn,Sn,Hn] scratch

  dim3 pgrid(Hn / 64, (Bn * Sn) / 64);

  // layer 1
  proj_gemm<<<pgrid, 256, 0, stream>>>(x, Wih, bih, xpws);
  rnn_rec<<<Bn, 1024, 0, stream>>>(xpws, Whh, bhh, h0, yout, fin);

  // layer 2 (input = y1 currently residing in d_out)
  proj_gemm<<<pgrid, 256, 0, stream>>>(yout, Wih + Hn * Hn, bih + Hn, xpws);
  rnn_rec<<<Bn, 1024, 0, stream>>>(xpws, Whh + Hn * Hn, bhh + Hn,
                                   h0 + Bn * Hn, yout, fin + Bn * Hn);
}

// Round 2
// 2818.425 us; speedup vs baseline: 1.0953x; 1.0953x over previous
//
#include <hip/hip_runtime.h>
#include <cstddef>

#define Bn 32
#define Sn 2048
#define Hn 256
#define Ln 2

__device__ __forceinline__ float tanh_fast(float x) {
  // tanh(x) = 1 - 2/(exp(2x)+1); saturates correctly at +/-inf
  float e = __expf(2.0f * x);
  return 1.0f - 2.0f / (e + 1.0f);
}

// ---------------------------------------------------------------------------
// Projection GEMM: C[M,N] = A[M,K] * W[N,K]^T + bias[N]   (unchanged)
// ---------------------------------------------------------------------------
__global__ __launch_bounds__(256) void proj_gemm(
    const float* __restrict__ A,
    const float* __restrict__ W,
    const float* __restrict__ bias,
    float* __restrict__ C)
{
  __shared__ float As[64][68];
  __shared__ float Bs[64][68];
  const int tid = threadIdx.x;
  const int tx = tid & 15;   // N direction
  const int ty = tid >> 4;   // M direction
  const size_t m0 = (size_t)blockIdx.y * 64;
  const int n0 = blockIdx.x * 64;

  float acc[4][4];
#pragma unroll
  for (int i = 0; i < 4; ++i)
#pragma unroll
    for (int j = 0; j < 4; ++j) acc[i][j] = 0.0f;

  for (int kc = 0; kc < Hn; kc += 64) {
#pragma unroll
    for (int r = 0; r < 4; ++r) {
      int idx = tid + 256 * r;
      int mm = idx >> 4;
      int kk = (idx & 15) << 2;
      float4 av = *(const float4*)&A[(m0 + (size_t)mm) * Hn + kc + kk];
      As[kk + 0][mm] = av.x; As[kk + 1][mm] = av.y;
      As[kk + 2][mm] = av.z; As[kk + 3][mm] = av.w;
      float4 wv = *(const float4*)&W[(size_t)(n0 + mm) * Hn + kc + kk];
      Bs[kk + 0][mm] = wv.x; Bs[kk + 1][mm] = wv.y;
      Bs[kk + 2][mm] = wv.z; Bs[kk + 3][mm] = wv.w;
    }
    __syncthreads();
#pragma unroll
    for (int k = 0; k < 64; ++k) {
      float4 a = *(const float4*)&As[k][ty << 2];
      float4 b = *(const float4*)&Bs[k][tx << 2];
      float av4[4] = {a.x, a.y, a.z, a.w};
      float bv4[4] = {b.x, b.y, b.z, b.w};
#pragma unroll
      for (int i = 0; i < 4; ++i)
#pragma unroll
        for (int j = 0; j < 4; ++j)
          acc[i][j] += av4[i] * bv4[j];
    }
    __syncthreads();
  }

  float4 bv = *(const float4*)&bias[n0 + (tx << 2)];
  float badd[4] = {bv.x, bv.y, bv.z, bv.w};
#pragma unroll
  for (int i = 0; i < 4; ++i) {
    float4 o;
    o.x = acc[i][0] + badd[0];
    o.y = acc[i][1] + badd[1];
    o.z = acc[i][2] + badd[2];
    o.w = acc[i][3] + badd[3];
    *(float4*)&C[(m0 + (size_t)((ty << 2) + i)) * Hn + n0 + (tx << 2)] = o;
  }
}

// ---------------------------------------------------------------------------
// Recurrence: one workgroup per batch, 512 threads (8 waves).
// Wave w owns k-chunk [32w,32w+32) AND outputs [32w,32w+32):
//   - Wreg[r][c] = Whh[lane+64r][32w+c]  (128 VGPRs = whole W on the CU)
//   - hv[32] wave-uniform (broadcast ds_read_b128, conflict-free)
//   - 128 FMAs/lane -> 4 partials, stored at part[9*o + w]:
//       write bank = (9*lane + w) mod 32, 9 odd -> 2 lanes/bank = FREE
//   - single barrier/step (raw s_barrier + lgkmcnt-only wait: y-stores and
//     the prefetched xp load stay in flight), partials double-buffered (s&1)
//     for WAR safety across the single barrier.
//   - reduce on ALL 64 lanes: lane l and l+32 share output o=32w+(l&31),
//     each sums 4 of the 8 slots (read bank 2-way = free), one
//     __shfl_xor(.,32) combines -> lanes 0-31 hold the full sum.
//   - h-update is wave-local (wave reads back only its own 32 outputs),
//     so no second barrier: same-wave LDS ops are in order.
// ---------------------------------------------------------------------------
#define PSTRIDE 9
#define PBUF (Hn * PSTRIDE)   // 2304 words per buffer

__global__ __launch_bounds__(512) void rnn_rec(
    const float* __restrict__ xp,   // [Bn,Sn,Hn] precomputed input projection
    const float* __restrict__ Whh,  // [Hn,Hn]
    const float* __restrict__ bhh,  // [Hn]
    const float* __restrict__ h0,   // [Bn,Hn] (layer slice)
    float* __restrict__ y,          // [Bn,Sn,Hn] layer outputs
    float* __restrict__ hfin)       // [Bn,Hn] final hidden (layer slice)
{
  const int b = blockIdx.x;
  const int t = threadIdx.x;
  const int lane = t & 63;
  const int w = t >> 6;            // 0..7
  const int ocol = 32 * w + (lane & 31);  // output this lane reduces
  const int hh = lane >> 5;        // which half of the 8 partial slots

  __shared__ float part[2 * PBUF]; // 2 x 9216 B
  __shared__ float hbuf[Hn];

  // Wreg[r][c] = Whh[lane + 64r][32w + c]
  float Wreg[4][32];
#pragma unroll
  for (int r = 0; r < 4; ++r)
#pragma unroll
    for (int q = 0; q < 8; ++q) {
      float4 v = *(const float4*)&Whh[(size_t)(lane + 64 * r) * Hn + 32 * w + 4 * q];
      Wreg[r][4 * q + 0] = v.x; Wreg[r][4 * q + 1] = v.y;
      Wreg[r][4 * q + 2] = v.z; Wreg[r][4 * q + 3] = v.w;
    }

  // partial-write base: part[9*(lane+64r) + w] = base + 576r (imm offsets)
  const int pw0 = PSTRIDE * lane + w;

  const float* xp_b = xp + (size_t)b * Sn * Hn;
  float* y_b = y + (size_t)b * Sn * Hn;
  const float bias = bhh[ocol];

  // initial hv from h0 (wave-uniform broadcast loads)
  float hv[32];
#pragma unroll
  for (int j = 0; j < 8; ++j)
    *(float4*)&hv[4 * j] = *(const float4*)&h0[(size_t)b * Hn + 32 * w + 4 * j];

  float xp_cur = xp_b[ocol];

  for (int s = 0; s < Sn; ++s) {
    // prefetch next step's xp; consumed after the barrier -> latency hidden
    float xp_next = (s + 1 < Sn) ? xp_b[(size_t)(s + 1) * Hn + ocol] : 0.0f;

    // ---- FMA phase: 128 fp32 FMAs/lane, all operands in registers
    float a0 = 0.f, a1 = 0.f, a2 = 0.f, a3 = 0.f;
#pragma unroll
    for (int c = 0; c < 32; ++c) {
      a0 += Wreg[0][c] * hv[c];
      a1 += Wreg[1][c] * hv[c];
      a2 += Wreg[2][c] * hv[c];
      a3 += Wreg[3][c] * hv[c];
    }
    float* pbuf = &part[(s & 1) * PBUF];
    pbuf[pw0       ] = a0;
    pbuf[pw0 +  576] = a1;
    pbuf[pw0 + 1152] = a2;
    pbuf[pw0 + 1728] = a3;

    // partials visible to all waves; no vmcnt drain (y/xp stay in flight)
    asm volatile("s_waitcnt lgkmcnt(0)" ::: "memory");
    __builtin_amdgcn_s_barrier();
    __builtin_amdgcn_sched_barrier(0);

    // ---- reduce: lane l sums slots [4*hh, 4*hh+4) of output ocol
    const float* prow = &pbuf[PSTRIDE * ocol + 4 * hh];
    float r0 = prow[0], r1 = prow[1], r2 = prow[2], r3 = prow[3];
    float s4 = (r0 + r1) + (r2 + r3);
    float tot = s4 + __shfl_xor(s4, 32, 64);
    float hn = tanh_fast(tot + xp_cur + bias);
    if (lane < 32) {
      hbuf[ocol] = hn;
      y_b[(size_t)s * Hn + ocol] = hn;   // fire-and-forget global store
    }
    xp_cur = xp_next;

    // ---- wave-local hv reload (only this wave's own 32 outputs)
    __builtin_amdgcn_wave_barrier();     // keep reads after the masked write
#pragma unroll
    for (int j = 0; j < 8; ++j)
      *(float4*)&hv[4 * j] = *(const float4*)&hbuf[32 * w + 4 * j];
  }

  if (lane < 32) hfin[(size_t)b * Hn + ocol] = hbuf[ocol];
}

// ---------------------------------------------------------------------------
// Phases (stream-ordered):
//  1. proj1: xp1 = x * Wih0^T + bih0          -> ws
//  2. rec1 : layer-1 recurrence, y1 -> d_out, fin0 -> d_out tail
//  3. proj2: xp2 = y1 * Wih1^T + bih1         -> ws (reuse)
//  4. rec2 : layer-2 recurrence, y2 -> d_out (final), fin1 -> d_out tail
// ws needs Bn*Sn*Hn*4 = 64 MiB.
// ---------------------------------------------------------------------------
extern "C" void kernel_launch(void* const* d_in, const int* in_sizes, int n_in,
                              void* d_out, int out_size, void* d_ws, size_t ws_size,
                              hipStream_t stream) {
  const float* x   = (const float*)d_in[0];
  const float* h0  = (const float*)d_in[1];
  const float* Wih = (const float*)d_in[2];
  const float* Whh = (const float*)d_in[3];
  const float* bih = (const float*)d_in[4];
  const float* bhh = (const float*)d_in[5];

  float* out = (float*)d_out;
  float* yout = out;                              // [Bn,Sn,Hn]
  float* fin  = out + (size_t)Bn * Sn * Hn;       // [Ln,Bn,Hn]
  float* xpws = (float*)d_ws;                     // [Bn,Sn,Hn] scratch

  dim3 pgrid(Hn / 64, (Bn * Sn) / 64);

  // layer 1
  proj_gemm<<<pgrid, 256, 0, stream>>>(x, Wih, bih, xpws);
  rnn_rec<<<Bn, 512, 0, stream>>>(xpws, Whh, bhh, h0, yout, fin);

  // layer 2 (input = y1 currently residing in d_out)
  proj_gemm<<<pgrid, 256, 0, stream>>>(yout, Wih + Hn * Hn, bih + Hn, xpws);
  rnn_rec<<<Bn, 512, 0, stream>>>(xpws, Whh + Hn * Hn, bhh + Hn,
                                  h0 + Bn * Hn, yout, fin + Bn * Hn);
}